// Round 6
// baseline (118.631 us; speedup 1.0000x reference)
//
#include <hip/hip_runtime.h>

typedef __bf16 bf16x8 __attribute__((ext_vector_type(8)));
typedef float f32x4 __attribute__((ext_vector_type(4)));
typedef float f32x16 __attribute__((ext_vector_type(16)));

#define CC 256
#define HH 48
#define WW 64
#define HW (HH * WW)
#define NB 8
#define GW 21

#define GLOAD_LDS16(g, l)                                                     \
    __builtin_amdgcn_global_load_lds(                                         \
        (const __attribute__((address_space(1))) unsigned int*)(g),           \
        (__attribute__((address_space(3))) unsigned int*)(l), 16, 0, 0)

// ---------------------------------------------------------------------------
// Prepass (unchanged): BOTH inputs -> MFMA-fragment PARITY order
//   [b][y][cblk=c>>3][p=x&1][x2=x>>1][c&7] bf16
// in1 scaled by 2^-8 (exact in bf16) to fold the /sumelems.
// ---------------------------------------------------------------------------
__global__ __launch_bounds__(256) void prep_kernel(const float* __restrict__ in1,
                                                   const float* __restrict__ in2,
                                                   unsigned short* __restrict__ o1,
                                                   unsigned short* __restrict__ o2)
{
    __shared__ float lds[CC * 33];
    int blk  = blockIdx.x;
    int sel  = (blk >= 768);
    int blk2 = sel ? blk - 768 : blk;
    int b  = blk2 & 7;
    int st = blk2 >> 3;
    int s0 = st * 32;
    const float* src = sel ? in2 : in1;
    unsigned short* dst = sel ? o2 : o1;
    float scale = sel ? 1.0f : (1.0f / 256.0f);

    int t = threadIdx.x;
    int sidx  = t & 31;
    int cbase = t >> 5;
    const float* sb = src + (size_t)b * CC * HW + s0;
    #pragma unroll
    for (int p = 0; p < 32; ++p) {
        int c = cbase + p * 8;
        lds[c * 33 + sidx] = sb[(size_t)c * HW + sidx] * scale;
    }
    __syncthreads();

    int y  = s0 >> 6;
    int xb = s0 & 63;
    int s  = t & 31;
    int c8 = t >> 5;
    unsigned short* db = dst + (size_t)(b * HH + y) * 32 * 64 * 8;
    int x = xb + s;
    int xoff = (x & 1) * 32 + (x >> 1);
    #pragma unroll
    for (int it = 0; it < 4; ++it) {
        int cblk = it * 8 + c8;
        unsigned dw[4];
        #pragma unroll
        for (int d = 0; d < 4; ++d) {
            unsigned u0 = __builtin_bit_cast(unsigned, lds[(cblk * 8 + 2 * d) * 33 + s]);
            u0 += 0x7fffu + ((u0 >> 16) & 1u);
            unsigned u1 = __builtin_bit_cast(unsigned, lds[(cblk * 8 + 2 * d + 1) * 33 + s]);
            u1 += 0x7fffu + ((u1 >> 16) & 1u);
            dw[d] = (u0 >> 16) | (u1 & 0xffff0000u);
        }
        *(uint4*)(db + ((size_t)cblk * 64 + xoff) * 8) =
            make_uint4(dw[0], dw[1], dw[2], dw[3]);
    }
}

// ---------------------------------------------------------------------------
// Main (R13 = R12 structure, ring bug fixed): ONE fat block per (b, ys0).
// R12's absmax 0.44 was the depth-3 A ring: (kk+3)%3 == kk%3, so the refill
// clobbered the slot consumed in the same iteration. Restored the PROVEN
// depth-4 ring (Ab[4], refill (kk+3)&3, consume kk&3) from R8/R10/R11.
// Structure under test (unchanged from R12):
//  - block = (b, ys0), 6 waves; wave w owns q in {w, w+6} (wave5: q=5).
//    All 22 j's of a ys0 share ONE 64KB B-stage (was 3x in R10/R11) and
//    each B-frag ds_read feeds 2 q's -> B LDS traffic per j halves.
//  - D^T has its own LDS region -> exactly ONE __syncthreads per block.
// Grid 8b x 88 ys0 = 704 blocks, ysrc-major, b = XCD affinity. LDS 118KB
// -> 1 block/CU, 6 waves. VGPR ~240 under the (384,2) 256 budget.
// ---------------------------------------------------------------------------
__global__ __launch_bounds__(384, 2) void corr_kernel(const unsigned short* __restrict__ in1F,
                                                      const unsigned short* __restrict__ in2F,
                                                      float* __restrict__ out)
{
    __shared__ unsigned char smem[120832];       // 64KB B rows + 6 x 9216B D^T
    unsigned short* Bl = (unsigned short*)smem;

    int blk = blockIdx.x;
    int b   = blk & 7;                           // batch == XCD affinity
    int yi  = blk >> 3;                          // 0..87, ysrc-major
    int ys0 = yi - 20;
    int ys1 = ys0 + 2;
    bool vs0 = (ys0 >= 0) && (ys0 < HH);
    bool vs1 = (ys1 >= 0) && (ys1 < HH);

    int tid  = threadIdx.x;
    int w    = tid >> 6;                         // 0..5
    int lane = tid & 63;
    int l31  = lane & 31;
    int q2   = lane >> 5;

    // wave w owns q-pairs {w, w+6}; wave 5 only q=5 (q=11 invalid)
    int q_[2];  q_[0] = w;  q_[1] = w + 6;
    int yo_[2]; yo_[0] = ys0 + 20 - 4 * q_[0];  yo_[1] = ys0 + 20 - 4 * q_[1];
    bool qv_[2];
    qv_[0] = (yo_[0] >= 0) && (yo_[0] < HH);
    qv_[1] = (q_[1] <= 10) && (yo_[1] >= 0) && (yo_[1] < HH);

    if (!vs0 && !vs1) {
        // both B rows OOB -> all owned output rows are zero; uniform exit
        #pragma unroll
        for (int qi = 0; qi < 2; ++qi) {
            if (!qv_[qi]) continue;
            #pragma unroll
            for (int jj = 0; jj < 2; ++jj) {
                int j = 2 * q_[qi] + jj;
                if (j > 20) continue;
                float* orow = out + (((size_t)(b * 441 + j * GW)) * HH + yo_[qi]) * WW;
                #pragma unroll
                for (int jx = 0; jx < GW; ++jx)
                    __builtin_nontemporal_store(0.0f, orow + (size_t)jx * HW + lane);
            }
        }
        return;
    }

    // A fragment bases (ushort units); frag(kk,p) at + kk*1024 + p*256
    const unsigned short* ar_[2];
    ar_[0] = in1F + (size_t)(b * HH + (qv_[0] ? yo_[0] : 0)) * 16384 + q2 * 512 + l31 * 8;
    ar_[1] = in1F + (size_t)(b * HH + (qv_[1] ? yo_[1] : 0)) * 16384 + q2 * 512 + l31 * 8;

    bf16x8 Ab[4][2][2], Bb[2][2][2];
    // ---- A prologue: ring slots 0..2 issued before the staging barrier ----
    #pragma unroll
    for (int s = 0; s < 3; ++s)
        #pragma unroll
        for (int qi = 0; qi < 2; ++qi)
            if (qv_[qi])
                #pragma unroll
                for (int p = 0; p < 2; ++p)
                    Ab[s][qi][p] = *(const bf16x8*)(ar_[qi] + s * 1024 + p * 256);

    // ---- stage the two B rows ONCE via global_load_lds (64 chunks of 1KB) ----
    for (int i = w; i < 64; i += 6) {
        int row = i >> 5, ch = i & 31;
        bool v = row ? vs1 : vs0;
        if (v) {
            const unsigned short* src = in2F
                + (size_t)(b * HH + (row ? ys1 : ys0)) * 16384 + ch * 512 + lane * 8;
            GLOAD_LDS16(src, Bl + row * 16384 + ch * 512);
        }
    }
    __syncthreads();                             // the ONLY barrier

    f32x16 acc[2][2][2];                         // [qi][jj][parity]
    #pragma unroll
    for (int qi = 0; qi < 2; ++qi)
        #pragma unroll
        for (int jj = 0; jj < 2; ++jj)
            #pragma unroll
            for (int p = 0; p < 2; ++p)
                acc[qi][jj][p] = (f32x16)(0.0f);

    int lofs = q2 * 512 + l31 * 8;               // fragment base within a row
    #pragma unroll
    for (int jj = 0; jj < 2; ++jj)
        if (jj ? vs1 : vs0)
            #pragma unroll
            for (int p = 0; p < 2; ++p)
                Bb[0][jj][p] = *(const bf16x8*)(Bl + jj * 16384 + lofs + p * 256);

    #pragma unroll
    for (int kk = 0; kk < 16; ++kk) {
        if (kk < 13) {                           // A ring refill, 3 iters ahead
            #pragma unroll
            for (int qi = 0; qi < 2; ++qi)
                if (qv_[qi])
                    #pragma unroll
                    for (int p = 0; p < 2; ++p)
                        Ab[(kk + 3) & 3][qi][p] =
                            *(const bf16x8*)(ar_[qi] + (size_t)(kk + 3) * 1024 + p * 256);
        }
        if (kk < 15) {                           // B double-buffer from LDS
            #pragma unroll
            for (int jj = 0; jj < 2; ++jj)
                if (jj ? vs1 : vs0)
                    #pragma unroll
                    for (int p = 0; p < 2; ++p)
                        Bb[(kk + 1) & 1][jj][p] =
                            *(const bf16x8*)(Bl + jj * 16384 + (kk + 1) * 1024 + lofs + p * 256);
        }
        #pragma unroll
        for (int qi = 0; qi < 2; ++qi)
            #pragma unroll
            for (int jj = 0; jj < 2; ++jj) {
                bool live = qv_[qi] && (jj ? vs1 : vs0);
                if (live)
                    #pragma unroll
                    for (int p = 0; p < 2; ++p)
                        acc[qi][jj][p] = __builtin_amdgcn_mfma_f32_32x32x16_bf16(
                            Ab[kk & 3][qi][p], Bb[kk & 1][jj][p], acc[qi][jj][p], 0, 0, 0);
            }
    }

    // Epilogue: wave-private D^T (own LDS region -> no barrier needed).
    // 32x32 C layout: col = l31 (n = ce), row = (r&3) + 8*(r>>2) + 4*q2 (m = xe).
    float* dtw = (float*)(smem + 65536) + w * 2304;   // [p][32 ce][36]
    int xe = lane >> 1;
    int pe = lane & 1;
    #pragma unroll
    for (int qi = 0; qi < 2; ++qi) {
        if (!qv_[qi]) continue;                  // wave-uniform
        #pragma unroll
        for (int jj = 0; jj < 2; ++jj) {
            int j = 2 * q_[qi] + jj;
            if (j > 20) continue;
            float* orow = out + (((size_t)(b * 441 + j * GW)) * HH + yo_[qi]) * WW;
            bool vsj = jj ? vs1 : vs0;           // block-uniform
            if (!vsj) {
                #pragma unroll
                for (int jx = 0; jx < GW; ++jx)
                    __builtin_nontemporal_store(0.0f, orow + (size_t)jx * HW + lane);
                continue;
            }
            #pragma unroll
            for (int p = 0; p < 2; ++p)
                #pragma unroll
                for (int rq = 0; rq < 4; ++rq) {
                    f32x4 v = { acc[qi][jj][p][4 * rq], acc[qi][jj][p][4 * rq + 1],
                                acc[qi][jj][p][4 * rq + 2], acc[qi][jj][p][4 * rq + 3] };
                    *(f32x4*)(dtw + (size_t)(p * 32 + l31) * 36 + rq * 8 + q2 * 4) = v;
                }
            #pragma unroll
            for (int jx = 0; jx < GW; ++jx) {
                int ce = xe + jx - 10;           // x = 2*xe+pe, colx = 2*ce+pe
                float val = (ce >= 0 && ce < 32)
                          ? dtw[(size_t)(pe * 32 + ce) * 36 + xe] : 0.0f;
                __builtin_nontemporal_store(val, orow + (size_t)jx * HW + lane);
            }
        }
    }
}

extern "C" void kernel_launch(void* const* d_in, const int* in_sizes, int n_in,
                              void* d_out, int out_size, void* d_ws, size_t ws_size,
                              hipStream_t stream)
{
    (void)in_sizes; (void)n_in; (void)out_size; (void)ws_size;
    const float* in1 = (const float*)d_in[0];
    const float* in2 = (const float*)d_in[1];
    float* out = (float*)d_out;

    unsigned short* in1F = (unsigned short*)d_ws;                 // 12.6 MB
    unsigned short* in2F = in1F + (size_t)NB * HW * CC;           // 12.6 MB

    prep_kernel<<<dim3(1536), dim3(256), 0, stream>>>(in1, in2, in1F, in2F);
    corr_kernel<<<dim3(NB * 88), dim3(384), 0, stream>>>(in1F, in2F, out);
}

// Round 7
// 115.832 us; speedup vs baseline: 1.0242x; 1.0242x over previous
//
#include <hip/hip_runtime.h>

typedef __bf16 bf16x8 __attribute__((ext_vector_type(8)));
typedef float f32x4 __attribute__((ext_vector_type(4)));
typedef float f32x16 __attribute__((ext_vector_type(16)));

#define CC 256
#define HH 48
#define WW 64
#define HW (HH * WW)
#define NB 8
#define GW 21

// ---------------------------------------------------------------------------
// Prepass (unchanged): BOTH inputs -> MFMA-fragment PARITY order
//   [b][y][cblk=c>>3][p=x&1][x2=x>>1][c&7] bf16
// in1 scaled by 2^-8 (exact in bf16) to fold the /sumelems.
// ---------------------------------------------------------------------------
__global__ __launch_bounds__(256) void prep_kernel(const float* __restrict__ in1,
                                                   const float* __restrict__ in2,
                                                   unsigned short* __restrict__ o1,
                                                   unsigned short* __restrict__ o2)
{
    __shared__ float lds[CC * 33];
    int blk  = blockIdx.x;
    int sel  = (blk >= 768);
    int blk2 = sel ? blk - 768 : blk;
    int b  = blk2 & 7;
    int st = blk2 >> 3;
    int s0 = st * 32;
    const float* src = sel ? in2 : in1;
    unsigned short* dst = sel ? o2 : o1;
    float scale = sel ? 1.0f : (1.0f / 256.0f);

    int t = threadIdx.x;
    int sidx  = t & 31;
    int cbase = t >> 5;
    const float* sb = src + (size_t)b * CC * HW + s0;
    #pragma unroll
    for (int p = 0; p < 32; ++p) {
        int c = cbase + p * 8;
        lds[c * 33 + sidx] = sb[(size_t)c * HW + sidx] * scale;
    }
    __syncthreads();

    int y  = s0 >> 6;
    int xb = s0 & 63;
    int s  = t & 31;
    int c8 = t >> 5;
    unsigned short* db = dst + (size_t)(b * HH + y) * 32 * 64 * 8;
    int x = xb + s;
    int xoff = (x & 1) * 32 + (x >> 1);
    #pragma unroll
    for (int it = 0; it < 4; ++it) {
        int cblk = it * 8 + c8;
        unsigned dw[4];
        #pragma unroll
        for (int d = 0; d < 4; ++d) {
            unsigned u0 = __builtin_bit_cast(unsigned, lds[(cblk * 8 + 2 * d) * 33 + s]);
            u0 += 0x7fffu + ((u0 >> 16) & 1u);
            unsigned u1 = __builtin_bit_cast(unsigned, lds[(cblk * 8 + 2 * d + 1) * 33 + s]);
            u1 += 0x7fffu + ((u1 >> 16) & 1u);
            dw[d] = (u0 >> 16) | (u1 & 0xffff0000u);
        }
        *(uint4*)(db + ((size_t)cblk * 64 + xoff) * 8) =
            make_uint4(dw[0], dw[1], dw[2], dw[3]);
    }
}

// ---------------------------------------------------------------------------
// Main (R14): ZERO-barrier, zero-staging, independent-wave structure.
// R7-R13: six structural variants (MFMA count, A-traffic, prefetch depth,
// staging path, barrier count, amortization) ALL null at corr~24.7us, while
// the port model says ~5us. Common factor: lockstep phase structure at <=8
// waves/CU (all waves hit the same stage/drain points). This kernel inverts
// that: one wave = one (b, ys0, q) computing the j-pair {2q, 2q+1}.
//  - B rows are XCD-local L2-resident (3.2MB/XCD) -> read DIRECTLY from
//    global, no LDS stage, no barrier (Common-mistake #7).
//  - A and B both use the proven depth-4/distance-3 register rings.
//  - D^T epilogue in wave-PRIVATE 9KB LDS -> no sync needed; idle waves
//    return immediately (safe: kernel has no barriers at all).
//  - 128-thr blocks (2 waves), 18KB LDS, launch_bounds(128,2): ~4 blocks/CU
//    = 8 INDEPENDENT waves/CU at different phases -> SIMD co-scheduling
//    (m114) overlaps one wave's loads with another's MFMA/epilogue.
// Grid 8b x 88 ys0 x 6 qh = 4224 blocks, ysrc-major, b = XCD affinity.
// ---------------------------------------------------------------------------
__global__ __launch_bounds__(128, 2) void corr_kernel(const unsigned short* __restrict__ in1F,
                                                      const unsigned short* __restrict__ in2F,
                                                      float* __restrict__ out)
{
    __shared__ float dts[2][2304];               // per-wave [pe][32 ce][36 xe]

    int blk = blockIdx.x;
    int b   = blk & 7;                           // batch == XCD affinity
    int r   = blk >> 3;                          // ysrc-major
    int yi  = r / 6;                             // 0..87
    int qh  = r - yi * 6;                        // 0..5
    int ys0 = yi - 20;
    int ys1 = ys0 + 2;

    int tid  = threadIdx.x;
    int w    = tid >> 6;                         // 0..1
    int lane = tid & 63;
    int q    = qh + 6 * w;                       // 0..11
    int yo   = ys0 + 20 - 4 * q;                 // output row (also A row)

    // idle waves exit immediately -- legal: no barriers in this kernel
    if (q > 10 || yo < 0 || yo >= HH) return;

    bool vs_[2];
    vs_[0] = (ys0 >= 0) && (ys0 < HH);
    vs_[1] = (ys1 >= 0) && (ys1 < HH);
    int j0 = 2 * q;

    int l31 = lane & 31;
    int q2  = lane >> 5;
    int lofs = q2 * 512 + l31 * 8;               // fragment base (ushort units)

    // operand bases; frag(kk,p) at + kk*1024 + p*256 (ushorts)
    const unsigned short* ar = in1F + (size_t)(b * HH + yo) * 16384 + lofs;
    const unsigned short* br_[2];
    br_[0] = in2F + (size_t)(b * HH + (vs_[0] ? ys0 : 0)) * 16384 + lofs;
    br_[1] = in2F + (size_t)(b * HH + (vs_[1] ? ys1 : 0)) * 16384 + lofs;

    // ---- depth-4 / distance-3 rings for BOTH A and B (proven pattern) ----
    bf16x8 Ab[4][2], Bb[4][2][2];
    #pragma unroll
    for (int s = 0; s < 3; ++s) {
        #pragma unroll
        for (int p = 0; p < 2; ++p)
            Ab[s][p] = *(const bf16x8*)(ar + s * 1024 + p * 256);
        #pragma unroll
        for (int jj = 0; jj < 2; ++jj)
            if (vs_[jj])
                #pragma unroll
                for (int p = 0; p < 2; ++p)
                    Bb[s][jj][p] = *(const bf16x8*)(br_[jj] + s * 1024 + p * 256);
    }

    f32x16 acc[2][2];                            // [jj][parity]
    #pragma unroll
    for (int jj = 0; jj < 2; ++jj)
        #pragma unroll
        for (int p = 0; p < 2; ++p)
            acc[jj][p] = (f32x16)(0.0f);

    #pragma unroll
    for (int kk = 0; kk < 16; ++kk) {
        if (kk < 13) {                           // refill slot kk+3, 3 iters ahead
            #pragma unroll
            for (int p = 0; p < 2; ++p)
                Ab[(kk + 3) & 3][p] =
                    *(const bf16x8*)(ar + (size_t)(kk + 3) * 1024 + p * 256);
            #pragma unroll
            for (int jj = 0; jj < 2; ++jj)
                if (vs_[jj])
                    #pragma unroll
                    for (int p = 0; p < 2; ++p)
                        Bb[(kk + 3) & 3][jj][p] =
                            *(const bf16x8*)(br_[jj] + (size_t)(kk + 3) * 1024 + p * 256);
        }
        #pragma unroll
        for (int jj = 0; jj < 2; ++jj)
            if (vs_[jj])
                #pragma unroll
                for (int p = 0; p < 2; ++p)
                    acc[jj][p] = __builtin_amdgcn_mfma_f32_32x32x16_bf16(
                        Ab[kk & 3][p], Bb[kk & 3][jj][p], acc[jj][p], 0, 0, 0);
    }

    // Epilogue: wave-private D^T dump + band extract, j0 then j1.
    // 32x32 C layout: col = l31 (n = ce), row = (r&3) + 8*(r>>2) + 4*q2 (m = xe).
    // Invalid-ysrc jj falls through with acc == 0 -> stores zeros (required).
    float* dtw = dts[w];
    int xe = lane >> 1;
    int pe = lane & 1;
    #pragma unroll
    for (int jj = 0; jj < 2; ++jj) {
        int j = j0 + jj;
        if (j > 20) continue;                    // q=10 has no j1
        float* orow = out + (((size_t)(b * 441 + j * GW)) * HH + yo) * WW;
        #pragma unroll
        for (int p = 0; p < 2; ++p)
            #pragma unroll
            for (int rq = 0; rq < 4; ++rq) {
                f32x4 v = { acc[jj][p][4 * rq], acc[jj][p][4 * rq + 1],
                            acc[jj][p][4 * rq + 2], acc[jj][p][4 * rq + 3] };
                *(f32x4*)(dtw + (size_t)(p * 32 + l31) * 36 + rq * 8 + q2 * 4) = v;
            }
        #pragma unroll
        for (int jx = 0; jx < GW; ++jx) {
            int ce = xe + jx - 10;               // x = 2*xe+pe, colx = 2*ce+pe
            float val = (ce >= 0 && ce < 32)
                      ? dtw[(size_t)(pe * 32 + ce) * 36 + xe] : 0.0f;
            __builtin_nontemporal_store(val, orow + (size_t)jx * HW + lane);
        }
    }
}

extern "C" void kernel_launch(void* const* d_in, const int* in_sizes, int n_in,
                              void* d_out, int out_size, void* d_ws, size_t ws_size,
                              hipStream_t stream)
{
    (void)in_sizes; (void)n_in; (void)out_size; (void)ws_size;
    const float* in1 = (const float*)d_in[0];
    const float* in2 = (const float*)d_in[1];
    float* out = (float*)d_out;

    unsigned short* in1F = (unsigned short*)d_ws;                 // 12.6 MB
    unsigned short* in2F = in1F + (size_t)NB * HW * CC;           // 12.6 MB

    prep_kernel<<<dim3(1536), dim3(256), 0, stream>>>(in1, in2, in1F, in2F);
    corr_kernel<<<dim3(NB * 88 * 6), dim3(128), 0, stream>>>(in1F, in2F, out);
}